// Round 2
// baseline (258.279 us; speedup 1.0000x reference)
//
#include <hip/hip_runtime.h>
#include <stdint.h>

#define NROWS 8192
#define DDIM  256
#define K2    512          // [hi | lo] packed per row
#define MARGIN_F 0.2f
#define MFMA16 __builtin_amdgcn_mfma_f32_16x16x32_bf16
#define SBAR0() __builtin_amdgcn_sched_barrier(0)

typedef short  short8  __attribute__((ext_vector_type(8)));
typedef float  floatx4 __attribute__((ext_vector_type(4)));

// Static device buffers (avoid depending on ws_size).
__device__ unsigned short gA[(size_t)NROWS * K2];   // im split: [hi | lo]
__device__ unsigned short gB[(size_t)NROWS * K2];   // s  split: [hi | lo]
__device__ float    g_diag[NROWS];
__device__ unsigned g_rowcnt[NROWS];
__device__ unsigned g_rowkey[NROWS];
__device__ unsigned g_colcnt[NROWS];
__device__ unsigned g_colkey[NROWS];

__device__ __forceinline__ unsigned short f2bf_rne(float x){
    unsigned u = __float_as_uint(x);
    return (unsigned short)((u + 0x7FFFu + ((u >> 16) & 1u)) >> 16);
}
__device__ __forceinline__ float bf2f(unsigned short h){
    return __uint_as_float(((unsigned)h) << 16);
}
// monotone float -> uint key (order-preserving), so atomicMax works on floats
__device__ __forceinline__ unsigned fkey(float f){
    unsigned u = __float_as_uint(f);
    return (u & 0x80000000u) ? ~u : (u | 0x80000000u);
}
__device__ __forceinline__ float kinv(unsigned k){
    unsigned u = (k & 0x80000000u) ? (k ^ 0x80000000u) : ~k;
    return __uint_as_float(u);
}

__device__ __forceinline__ void load_lds16(const unsigned short* gptr, void* lptr){
    __builtin_amdgcn_global_load_lds(
        (const __attribute__((address_space(1))) unsigned int*)(uintptr_t)gptr,
        (__attribute__((address_space(3))) unsigned int*)(unsigned)(uintptr_t)lptr,
        16, 0, 0);
}

// One wave per row: fp32 diag dot, hi/lo bf16 split, stats init.
__global__ __launch_bounds__(256) void prep_kernel(const float* __restrict__ im,
                                                   const float* __restrict__ s){
    const int w    = threadIdx.x >> 6;
    const int lane = threadIdx.x & 63;
    const int row  = blockIdx.x * 4 + w;

    const float4 a = ((const float4*)(im + (size_t)row * DDIM))[lane];
    const float4 b = ((const float4*)(s  + (size_t)row * DDIM))[lane];

    float dp = a.x*b.x + a.y*b.y + a.z*b.z + a.w*b.w;
    #pragma unroll
    for (int m = 1; m < 64; m <<= 1) dp += __shfl_xor(dp, m, 64);
    if (lane == 0){
        g_diag[row]   = dp;
        g_rowcnt[row] = 0u; g_rowkey[row] = 0u;
        g_colcnt[row] = 0u; g_colkey[row] = 0u;
    }

    float av[4] = {a.x, a.y, a.z, a.w};
    float bv[4] = {b.x, b.y, b.z, b.w};
    unsigned short ah[4], al[4], bh[4], bl[4];
    #pragma unroll
    for (int i = 0; i < 4; ++i){
        ah[i] = f2bf_rne(av[i]); al[i] = f2bf_rne(av[i] - bf2f(ah[i]));
        bh[i] = f2bf_rne(bv[i]); bl[i] = f2bf_rne(bv[i] - bf2f(bh[i]));
    }
    const size_t base = (size_t)row * K2 + lane * 4;
    *(ushort4*)&gA[base      ] = make_ushort4(ah[0], ah[1], ah[2], ah[3]);
    *(ushort4*)&gA[base + 256] = make_ushort4(al[0], al[1], al[2], al[3]);
    *(ushort4*)&gB[base      ] = make_ushort4(bh[0], bh[1], bh[2], bh[3]);
    *(ushort4*)&gB[base + 256] = make_ushort4(bl[0], bl[1], bl[2], bl[3]);
}

// Stage one 8KB unit: 128 rows x 32 shorts of B, hi (hl=0) or lo (hl=1) of
// k-chunk c. Chunk-level XOR swizzle (same as R11, verified absmax 0):
// stored (r, cpos) holds logical 16B-chunk cpos ^ ((r>>1)&3); reader uses
// co = (quad ^ ((l16>>1)&3))*8. Source pre-swizzled, LDS dest linear.
__device__ __forceinline__ void stage_unit(const unsigned short* __restrict__ Bbase,
                                           int c, int hl, unsigned short* sb, int tid){
    #pragma unroll
    for (int q = 0; q < 2; ++q){
        const int o    = q * 4096 + tid * 16;     // byte offset in 8KB unit
        const int ch   = o >> 4;
        const int r    = ch >> 2;
        const int clog = (ch & 3) ^ ((r >> 1) & 3);
        const size_t goff = (size_t)r * K2 + (size_t)c * 32 + (size_t)hl * 256 + clog * 8;
        load_lds16(Bbase + goff, (char*)sb + o);
    }
}

// 128x128 tile, 4 waves of 32x128, 16x16x32 bf16 MFMA, 3-pass hi/lo split.
// R12 vs R11: the barrier drain WAS the stall (R11's dbuf regressed because
// __syncthreads == s_waitcnt vmcnt(0) drains the just-issued prefetch every
// phase). Now: raw s_barrier + counted vmcnt (T3+T4). 16 phases = 8 k-chunks
// x {Bh phase: pass1+2, Bl phase: pass3}; 4-slot ring of 8KB units; phase p
// stages unit p+3 (2 units always in flight); end-of-phase wait vmcnt(8)
// targets a unit issued TWO phases earlier -> free in steady state. A frags
// ping-pong between two named register sets (2-chunk manual unroll, no
// copies, all slot indices compile-time). drow/dcol LDS dropped (epilogue
// reads g_diag direct) -> LDS = 32KB exactly, 4 blocks/CU kept.
// Per-element MFMA accumulation order identical to R11 (pass1,2,3 per chunk).
__global__ __launch_bounds__(256, 4) void gemm_stats_kernel(){
    __shared__ unsigned short SB[4][128 * 32];   // 4 x 8KB ring

    const int tid = threadIdx.x;
    const int bid = blockIdx.x;
    // bid[2:0]->band(XCD), bid[5:3]->row within band, bid[11:6]->column
    const int bi  = (bid & 7) * 8 + ((bid >> 3) & 7);
    const int bj  = bid >> 6;

    const int w    = tid >> 6, lane = tid & 63;
    const int quad = lane >> 4, l16 = lane & 15;
    const int co   = (quad ^ ((l16 >> 1) & 3)) * 8;   // read-side swizzle

    floatx4 acc[2][8] = {};

    const unsigned short* Abase = gA + (size_t)bi * 128 * K2;
    const unsigned short* Bbase = gB + (size_t)bj * 128 * K2;
    // MFMA A layout: lane(l16,quad) -> row l16, k quad*8+j. Wave w owns rows
    // w*32..w*32+31 (mi selects 16-row half).
    const unsigned short* AhFrag = Abase + (size_t)(w * 32 + l16) * K2 + quad * 8;
    const unsigned short* AlFrag = AhFrag + 256;

    // Two A register sets (ping-pong across chunks; no copies).
    short8 AH00, AH01, AL00, AL01;   // set 0
    short8 AH10, AH11, AL10, AL11;   // set 1

    auto load_a = [&](int cn, short8& h0, short8& h1, short8& l0, short8& l1){
        h0 = *(const short8*)(AhFrag + (size_t)cn * 32);
        h1 = *(const short8*)(AhFrag + (size_t)16 * K2 + (size_t)cn * 32);
        l0 = *(const short8*)(AlFrag + (size_t)cn * 32);
        l1 = *(const short8*)(AlFrag + (size_t)16 * K2 + (size_t)cn * 32);
    };
    // Bh phase: pass1 (Ah*Bh) + pass2 (Al*Bh)
    auto even_phase = [&](const unsigned short* sb, const short8& xh0, const short8& xh1,
                          const short8& xl0, const short8& xl1){
        #pragma unroll
        for (int h2 = 0; h2 < 2; ++h2){
            short8 b4[4];
            #pragma unroll
            for (int j = 0; j < 4; ++j)
                b4[j] = *(const short8*)&sb[((h2*4 + j) * 16 + l16) * 32 + co];
            #pragma unroll
            for (int j = 0; j < 4; ++j){
                acc[0][h2*4+j] = MFMA16(xh0, b4[j], acc[0][h2*4+j], 0, 0, 0);
                acc[1][h2*4+j] = MFMA16(xh1, b4[j], acc[1][h2*4+j], 0, 0, 0);
            }
            #pragma unroll
            for (int j = 0; j < 4; ++j){
                acc[0][h2*4+j] = MFMA16(xl0, b4[j], acc[0][h2*4+j], 0, 0, 0);
                acc[1][h2*4+j] = MFMA16(xl1, b4[j], acc[1][h2*4+j], 0, 0, 0);
            }
        }
    };
    // Bl phase: pass3 (Ah*Bl)
    auto odd_phase = [&](const unsigned short* sb, const short8& xh0, const short8& xh1){
        #pragma unroll
        for (int h2 = 0; h2 < 2; ++h2){
            short8 b4[4];
            #pragma unroll
            for (int j = 0; j < 4; ++j)
                b4[j] = *(const short8*)&sb[((h2*4 + j) * 16 + l16) * 32 + co];
            #pragma unroll
            for (int j = 0; j < 4; ++j){
                acc[0][h2*4+j] = MFMA16(xh0, b4[j], acc[0][h2*4+j], 0, 0, 0);
                acc[1][h2*4+j] = MFMA16(xh1, b4[j], acc[1][h2*4+j], 0, 0, 0);
            }
        }
    };

    // ---- prologue: units 0,1,2 (chunk0 hi/lo, chunk1 hi); A chunk 0 ----
    stage_unit(Bbase, 0, 0, SB[0], tid);
    stage_unit(Bbase, 0, 1, SB[1], tid);
    stage_unit(Bbase, 1, 0, SB[2], tid);
    SBAR0();
    load_a(0, AH00, AH01, AL00, AL01);
    SBAR0();
    asm volatile("s_waitcnt vmcnt(8)");      // unit 0 done (8 newer ops allowed)
    __builtin_amdgcn_s_barrier();
    SBAR0();

    // ---- main: 3 iterations x 2 chunks x 2 phases (phases 0..11) ----
    #pragma unroll 1
    for (int c2 = 0; c2 < 3; ++c2){
        const int c = 2 * c2;
        // phase 4c2+0: chunk c, Bh (set 0). stage unit 4c2+3 = (c+1, lo)
        stage_unit(Bbase, c + 1, 1, SB[3], tid);
        SBAR0();
        even_phase(SB[0], AH00, AH01, AL00, AL01);
        asm volatile("s_waitcnt vmcnt(8)");
        __builtin_amdgcn_s_barrier();
        SBAR0();
        // phase 4c2+1: chunk c, Bl (set 0). A(c+1)->set1; stage (c+2, hi)
        load_a(c + 1, AH10, AH11, AL10, AL11);
        SBAR0();
        stage_unit(Bbase, c + 2, 0, SB[0], tid);
        SBAR0();
        odd_phase(SB[1], AH00, AH01);
        asm volatile("s_waitcnt vmcnt(8)");
        __builtin_amdgcn_s_barrier();
        SBAR0();
        // phase 4c2+2: chunk c+1, Bh (set 1). stage (c+2, lo)
        stage_unit(Bbase, c + 2, 1, SB[1], tid);
        SBAR0();
        even_phase(SB[2], AH10, AH11, AL10, AL11);
        asm volatile("s_waitcnt vmcnt(8)");
        __builtin_amdgcn_s_barrier();
        SBAR0();
        // phase 4c2+3: chunk c+1, Bl (set 1). A(c+2)->set0; stage (c+3, hi)
        load_a(c + 2, AH00, AH01, AL00, AL01);
        SBAR0();
        stage_unit(Bbase, c + 3, 0, SB[2], tid);
        SBAR0();
        odd_phase(SB[3], AH10, AH11);
        asm volatile("s_waitcnt vmcnt(8)");
        __builtin_amdgcn_s_barrier();
        SBAR0();
    }

    // ---- tail: chunks 6,7 (phases 12..15); set0 holds A(6) ----
    // phase 12: chunk 6 Bh. stage unit 15 = (7, lo)
    stage_unit(Bbase, 7, 1, SB[3], tid);
    SBAR0();
    even_phase(SB[0], AH00, AH01, AL00, AL01);
    asm volatile("s_waitcnt vmcnt(8)");
    __builtin_amdgcn_s_barrier();
    SBAR0();
    // phase 13: chunk 6 Bl. A(7)->set1; no stage (unit 16 doesn't exist)
    load_a(7, AH10, AH11, AL10, AL11);
    SBAR0();
    odd_phase(SB[1], AH00, AH01);
    asm volatile("s_waitcnt vmcnt(6)");      // unit 14: newer = S(u15)2 + A(7)4
    __builtin_amdgcn_s_barrier();
    SBAR0();
    // phase 14: chunk 7 Bh
    even_phase(SB[2], AH10, AH11, AL10, AL11);
    asm volatile("s_waitcnt vmcnt(0)");      // unit 15: nothing newer remains
    __builtin_amdgcn_s_barrier();
    SBAR0();
    // phase 15: chunk 7 Bl (no barrier needed after: acc is register-only)
    odd_phase(SB[3], AH10, AH11);

    // ---- fused stats epilogue ----
    // C/D layout (verified m89/m91): col = lane&15, row = quad*4 + reg.
    // acc[mi][nj]: row = w*32 + mi*16 + quad*4 + r ; col = nj*16 + l16.
    const int rowbase = bi * 128 + w * 32;
    const int colbase = bj * 128;

    // row stats: each lane holds 8 cols (nj); reduce across l16 lanes.
    #pragma unroll
    for (int mi = 0; mi < 2; ++mi){
        #pragma unroll
        for (int r = 0; r < 4; ++r){
            const int gi = rowbase + mi * 16 + quad * 4 + r;
            const float dv = g_diag[gi];
            int cnt = 0; float mx = -3.0e38f;
            #pragma unroll
            for (int nj = 0; nj < 8; ++nj){
                const float v  = acc[mi][nj][r];
                const int   gj = colbase + nj * 16 + l16;
                if (gi != gj){                 // exclude diagonal explicitly
                    cnt += (v < dv) ? 1 : 0;
                    mx = fmaxf(mx, v);
                }
            }
            #pragma unroll
            for (int m = 1; m < 16; m <<= 1){
                cnt += __shfl_xor(cnt, m, 64);
                mx   = fmaxf(mx, __shfl_xor(mx, m, 64));
            }
            if (l16 == 0){
                atomicAdd(&g_rowcnt[gi], (unsigned)cnt);
                atomicMax(&g_rowkey[gi], fkey(mx));
            }
        }
    }
    // col stats: each lane holds 8 rows (mi,r) per nj; reduce across quads.
    #pragma unroll
    for (int nj = 0; nj < 8; ++nj){
        const int gj = colbase + nj * 16 + l16;
        const float dv = g_diag[gj];
        int cnt = 0; float mx = -3.0e38f;
        #pragma unroll
        for (int mi = 0; mi < 2; ++mi){
            #pragma unroll
            for (int r = 0; r < 4; ++r){
                const float v  = acc[mi][nj][r];
                const int   gi = rowbase + mi * 16 + quad * 4 + r;
                if (gi != gj){
                    cnt += (v < dv) ? 1 : 0;
                    mx = fmaxf(mx, v);
                }
            }
        }
        #pragma unroll
        for (int m = 16; m < 64; m <<= 1){
            cnt += __shfl_xor(cnt, m, 64);
            mx   = fmaxf(mx, __shfl_xor(mx, m, 64));
        }
        if (quad == 0){
            atomicAdd(&g_colcnt[gj], (unsigned)cnt);
            atomicMax(&g_colkey[gj], fkey(mx));
        }
    }
}

__global__ __launch_bounds__(256) void finalize_kernel(float* __restrict__ out){
    __shared__ double red[256];
    double acc = 0.0;
    #pragma unroll
    for (int it = 0; it < NROWS / 256; ++it){
        const int i = it * 256 + threadIdx.x;
        const float d  = g_diag[i];
        const float cs  = fmaxf(MARGIN_F + kinv(g_rowkey[i]) - d, 0.0f) * (1.0f / (float)(g_rowcnt[i] + 1u));
        const float cim = fmaxf(MARGIN_F + kinv(g_colkey[i]) - d, 0.0f) * (1.0f / (float)(g_colcnt[i] + 1u));
        acc += (double)cs + (double)cim;
    }
    red[threadIdx.x] = acc;
    __syncthreads();
    for (int s2 = 128; s2 > 0; s2 >>= 1){
        if (threadIdx.x < s2) red[threadIdx.x] += red[threadIdx.x + s2];
        __syncthreads();
    }
    if (threadIdx.x == 0) out[0] = (float)red[0];
}

extern "C" void kernel_launch(void* const* d_in, const int* in_sizes, int n_in,
                              void* d_out, int out_size, void* d_ws, size_t ws_size,
                              hipStream_t stream){
    const float* im = (const float*)d_in[0];
    const float* s  = (const float*)d_in[1];
    float* out = (float*)d_out;

    prep_kernel<<<NROWS / 4, 256, 0, stream>>>(im, s);
    gemm_stats_kernel<<<4096, 256, 0, stream>>>();
    finalize_kernel<<<1, 256, 0, stream>>>(out);
}

// Round 3
// 252.230 us; speedup vs baseline: 1.0240x; 1.0240x over previous
//
#include <hip/hip_runtime.h>
#include <stdint.h>

#define NROWS 8192
#define DDIM  256
#define K2    512          // [hi | lo] packed per row
#define MARGIN_F 0.2f
#define MFMA16 __builtin_amdgcn_mfma_f32_16x16x32_bf16
#define SBAR0() __builtin_amdgcn_sched_barrier(0)

typedef short  short8  __attribute__((ext_vector_type(8)));
typedef float  floatx4 __attribute__((ext_vector_type(4)));

// Static device buffers (avoid depending on ws_size).
__device__ unsigned short gA[(size_t)NROWS * K2];   // im split: [hi | lo]
__device__ unsigned short gB[(size_t)NROWS * K2];   // s  split: [hi | lo]
__device__ float    g_diag[NROWS];
__device__ unsigned g_rowcnt[NROWS];
__device__ unsigned g_rowkey[NROWS];
__device__ unsigned g_colcnt[NROWS];
__device__ unsigned g_colkey[NROWS];

__device__ __forceinline__ unsigned short f2bf_rne(float x){
    unsigned u = __float_as_uint(x);
    return (unsigned short)((u + 0x7FFFu + ((u >> 16) & 1u)) >> 16);
}
__device__ __forceinline__ float bf2f(unsigned short h){
    return __uint_as_float(((unsigned)h) << 16);
}
// monotone float -> uint key (order-preserving), so atomicMax works on floats
__device__ __forceinline__ unsigned fkey(float f){
    unsigned u = __float_as_uint(f);
    return (u & 0x80000000u) ? ~u : (u | 0x80000000u);
}
__device__ __forceinline__ float kinv(unsigned k){
    unsigned u = (k & 0x80000000u) ? (k ^ 0x80000000u) : ~k;
    return __uint_as_float(u);
}

__device__ __forceinline__ void load_lds16(const unsigned short* gptr, void* lptr){
    __builtin_amdgcn_global_load_lds(
        (const __attribute__((address_space(1))) unsigned int*)(uintptr_t)gptr,
        (__attribute__((address_space(3))) unsigned int*)(unsigned)(uintptr_t)lptr,
        16, 0, 0);
}

// One wave per row: fp32 diag dot, hi/lo bf16 split, stats init.
__global__ __launch_bounds__(256) void prep_kernel(const float* __restrict__ im,
                                                   const float* __restrict__ s){
    const int w    = threadIdx.x >> 6;
    const int lane = threadIdx.x & 63;
    const int row  = blockIdx.x * 4 + w;

    const float4 a = ((const float4*)(im + (size_t)row * DDIM))[lane];
    const float4 b = ((const float4*)(s  + (size_t)row * DDIM))[lane];

    float dp = a.x*b.x + a.y*b.y + a.z*b.z + a.w*b.w;
    #pragma unroll
    for (int m = 1; m < 64; m <<= 1) dp += __shfl_xor(dp, m, 64);
    if (lane == 0){
        g_diag[row]   = dp;
        g_rowcnt[row] = 0u; g_rowkey[row] = 0u;
        g_colcnt[row] = 0u; g_colkey[row] = 0u;
    }

    float av[4] = {a.x, a.y, a.z, a.w};
    float bv[4] = {b.x, b.y, b.z, b.w};
    unsigned short ah[4], al[4], bh[4], bl[4];
    #pragma unroll
    for (int i = 0; i < 4; ++i){
        ah[i] = f2bf_rne(av[i]); al[i] = f2bf_rne(av[i] - bf2f(ah[i]));
        bh[i] = f2bf_rne(bv[i]); bl[i] = f2bf_rne(bv[i] - bf2f(bh[i]));
    }
    const size_t base = (size_t)row * K2 + lane * 4;
    *(ushort4*)&gA[base      ] = make_ushort4(ah[0], ah[1], ah[2], ah[3]);
    *(ushort4*)&gA[base + 256] = make_ushort4(al[0], al[1], al[2], al[3]);
    *(ushort4*)&gB[base      ] = make_ushort4(bh[0], bh[1], bh[2], bh[3]);
    *(ushort4*)&gB[base + 256] = make_ushort4(bl[0], bl[1], bl[2], bl[3]);
}

// Stage one 16KB unit: 256 rows x 32 shorts (one 32-k chunk, hi or lo) of an
// operand tile, 512 threads x 2 x 16B DMA ops. Slot swizzle: physical 16B
// slot sp in row r holds logical k-slot sp ^ ((r>>1)&3) -> frag reads hit
// each bank exactly 8x (uniform = conflict-free for b128). Source address
// pre-swizzled, LDS dest linear (global_load_lds constraint).
__device__ __forceinline__ void stage_unit256(const unsigned short* __restrict__ Obase,
                                              int c, int hl, unsigned short* sb, int tid){
    #pragma unroll
    for (int q2 = 0; q2 < 2; ++q2){
        const int o  = q2 * 8192 + tid * 16;    // dest byte in 16KB unit
        const int r  = o >> 6;                  // row 0..255 (64B rows)
        const int sp = (o >> 4) & 3;            // physical slot
        const int ql = sp ^ ((r >> 1) & 3);     // logical k-slot
        const size_t goff = (size_t)r * K2 + (size_t)c * 32 + (size_t)hl * 256 + (size_t)ql * 8;
        load_lds16(Obase + goff, (char*)sb + o);
    }
}

// 256x256 tile, 8 waves (2Mx4N, 128x64 per wave), 16x16x32 bf16, 3-pass hi/lo.
// R13 vs R12: STRUCTURE change, not schedule tweak. Three schedules at 128²
// all pinned at ~195us / 22% MfmaUtil -> the 128²/16-wave/small-phase family
// is the wall (m233: 2-phase overhead ~72%). Port of the verified 256²
// deep-phase template (m196-m201: 62% MfmaUtil): 1024 blocks = 4 rounds of
// 1 block/CU, 512 thr, 128KB LDS (8 x 16KB units: Ah/Bh/Al/Bl double-buf).
// A is now staged coalesced via DMA too (kills the 16-line A gathers).
// Per chunk c (32 k): P1 pass1(Ah*Bh), P2 pass2(Al*Bh, Bh held in regs),
// P3 pass3(Ah*Bl). Each phase: stage next-chunk unit(s), counted vmcnt(8)
// (per-chunk ops/thread = 4+2+2 = 8 -> uniform; tail 4/2/0), barrier,
// ds_reads, setprio'd 32-MFMA cluster, barrier. Per-element accumulation
// order identical to R10-R12 (same 32-k windows, pass1->2->3) => absmax 0.
__global__ __launch_bounds__(512, 2) void gemm_stats_kernel(){
    __shared__ unsigned short U[8][256 * 32];   // [0+d]=Ah, [2+d]=Bh, [4+d]=Al, [6+d]=Bl

    const int tid = threadIdx.x;
    const int bid = blockIdx.x;
    // bid[2:0]->XCD band of bi, bid[4:3]->bi within band, bid[9:5]->bj
    const int bi  = (bid & 7) * 4 + ((bid >> 3) & 3);
    const int bj  = bid >> 5;

    const int w    = tid >> 6, lane = tid & 63;
    const int quad = lane >> 4, l16 = lane & 15;
    const int wr   = w >> 2,   wc  = w & 3;
    const int sel  = (quad ^ ((l16 >> 1) & 3)) << 4;   // swizzled 16B slot
    const int aoff = (wr * 128 + l16) * 64 + sel;      // byte off in A units
    const int boff = (wc * 64  + l16) * 64 + sel;      // byte off in B units

    floatx4 acc[8][4] = {};

    const unsigned short* Abase = gA + (size_t)bi * 256 * K2;
    const unsigned short* Bbase = gB + (size_t)bj * 256 * K2;

    auto ld_a = [&](const unsigned short* u, short8 (&f)[8]){
        #pragma unroll
        for (int mi = 0; mi < 8; ++mi)
            f[mi] = *(const short8*)((const char*)u + aoff + mi * 1024);
    };
    auto ld_b = [&](const unsigned short* u, short8 (&f)[4]){
        #pragma unroll
        for (int nj = 0; nj < 4; ++nj)
            f[nj] = *(const short8*)((const char*)u + boff + nj * 1024);
    };
    auto mfma32 = [&](const short8 (&a)[8], const short8 (&b)[4]){
        __builtin_amdgcn_s_setprio(1);
        #pragma unroll
        for (int mi = 0; mi < 8; ++mi)
            #pragma unroll
            for (int nj = 0; nj < 4; ++nj)
                acc[mi][nj] = MFMA16(a[mi], b[nj], acc[mi][nj], 0, 0, 0);
        __builtin_amdgcn_s_setprio(0);
    };

    // ---- prologue: chunk 0's four units into buffer 0 ----
    stage_unit256(Abase, 0, 0, U[0], tid);
    stage_unit256(Bbase, 0, 0, U[2], tid);
    stage_unit256(Abase, 0, 1, U[4], tid);
    stage_unit256(Bbase, 0, 1, U[6], tid);

    #pragma unroll 1
    for (int c = 0; c < 7; ++c){
        const int d = c & 1, e = d ^ 1;
        short8 bh[4];
        // ---- P1: pass1 = Ah*Bh; stage next Ah,Bh ----
        stage_unit256(Abase, c + 1, 0, U[0 + e], tid);
        stage_unit256(Bbase, c + 1, 0, U[2 + e], tid);
        SBAR0();
        asm volatile("s_waitcnt vmcnt(8)" ::: "memory");
        __builtin_amdgcn_s_barrier();
        SBAR0();
        {
            short8 ah[8];
            ld_a(U[0 + d], ah); ld_b(U[2 + d], bh);
            mfma32(ah, bh);
        }
        __builtin_amdgcn_s_barrier();
        // ---- P2: pass2 = Al*Bh (bh held); stage next Al ----
        stage_unit256(Abase, c + 1, 1, U[4 + e], tid);
        SBAR0();
        asm volatile("s_waitcnt vmcnt(8)" ::: "memory");
        __builtin_amdgcn_s_barrier();
        SBAR0();
        {
            short8 al[8];
            ld_a(U[4 + d], al);
            mfma32(al, bh);
        }
        __builtin_amdgcn_s_barrier();
        // ---- P3: pass3 = Ah*Bl; stage next Bl ----
        stage_unit256(Bbase, c + 1, 1, U[6 + e], tid);
        SBAR0();
        asm volatile("s_waitcnt vmcnt(8)" ::: "memory");
        __builtin_amdgcn_s_barrier();
        SBAR0();
        {
            short8 ah2[8], bl[4];
            ld_a(U[0 + d], ah2); ld_b(U[6 + d], bl);
            mfma32(ah2, bl);
        }
        __builtin_amdgcn_s_barrier();
    }
    // ---- tail chunk 7 (d=1): no staging; drain 4 -> 2 -> 0 ----
    {
        short8 bh[4];
        asm volatile("s_waitcnt vmcnt(4)" ::: "memory");
        __builtin_amdgcn_s_barrier();
        SBAR0();
        {
            short8 ah[8];
            ld_a(U[1], ah); ld_b(U[3], bh);
            mfma32(ah, bh);
        }
        __builtin_amdgcn_s_barrier();
        asm volatile("s_waitcnt vmcnt(2)" ::: "memory");
        __builtin_amdgcn_s_barrier();
        SBAR0();
        {
            short8 al[8];
            ld_a(U[5], al);
            mfma32(al, bh);
        }
        __builtin_amdgcn_s_barrier();
        asm volatile("s_waitcnt vmcnt(0)" ::: "memory");
        __builtin_amdgcn_s_barrier();
        SBAR0();
        {
            short8 ah2[8], bl[4];
            ld_a(U[1], ah2); ld_b(U[7], bl);
            mfma32(ah2, bl);
        }
    }

    // ---- fused stats epilogue ----
    // C/D layout (verified m89/m91): col = lane&15, row = quad*4 + reg.
    // acc[mi][nj]: row = wr*128 + mi*16 + quad*4 + r ; col = wc*64 + nj*16 + l16.
    const int rowbase = bi * 256 + wr * 128;
    const int colbase = bj * 256 + wc * 64;

    // row stats: each lane holds 4 cols (nj); reduce across l16 lanes.
    #pragma unroll
    for (int mi = 0; mi < 8; ++mi){
        #pragma unroll
        for (int r = 0; r < 4; ++r){
            const int gi = rowbase + mi * 16 + quad * 4 + r;
            const float dv = g_diag[gi];
            int cnt = 0; float mx = -3.0e38f;
            #pragma unroll
            for (int nj = 0; nj < 4; ++nj){
                const float v  = acc[mi][nj][r];
                const int   gj = colbase + nj * 16 + l16;
                if (gi != gj){                 // exclude diagonal explicitly
                    cnt += (v < dv) ? 1 : 0;
                    mx = fmaxf(mx, v);
                }
            }
            #pragma unroll
            for (int m = 1; m < 16; m <<= 1){
                cnt += __shfl_xor(cnt, m, 64);
                mx   = fmaxf(mx, __shfl_xor(mx, m, 64));
            }
            if (l16 == 0){
                atomicAdd(&g_rowcnt[gi], (unsigned)cnt);
                atomicMax(&g_rowkey[gi], fkey(mx));
            }
        }
    }
    // col stats: each lane holds 32 rows (mi,r) per nj; reduce across quads.
    #pragma unroll
    for (int nj = 0; nj < 4; ++nj){
        const int gj = colbase + nj * 16 + l16;
        const float dv = g_diag[gj];
        int cnt = 0; float mx = -3.0e38f;
        #pragma unroll
        for (int mi = 0; mi < 8; ++mi){
            #pragma unroll
            for (int r = 0; r < 4; ++r){
                const float v  = acc[mi][nj][r];
                const int   gi = rowbase + mi * 16 + quad * 4 + r;
                if (gi != gj){
                    cnt += (v < dv) ? 1 : 0;
                    mx = fmaxf(mx, v);
                }
            }
        }
        #pragma unroll
        for (int m = 16; m < 64; m <<= 1){
            cnt += __shfl_xor(cnt, m, 64);
            mx   = fmaxf(mx, __shfl_xor(mx, m, 64));
        }
        if (quad == 0){
            atomicAdd(&g_colcnt[gj], (unsigned)cnt);
            atomicMax(&g_colkey[gj], fkey(mx));
        }
    }
}

__global__ __launch_bounds__(256) void finalize_kernel(float* __restrict__ out){
    __shared__ double red[256];
    double acc = 0.0;
    #pragma unroll
    for (int it = 0; it < NROWS / 256; ++it){
        const int i = it * 256 + threadIdx.x;
        const float d  = g_diag[i];
        const float cs  = fmaxf(MARGIN_F + kinv(g_rowkey[i]) - d, 0.0f) * (1.0f / (float)(g_rowcnt[i] + 1u));
        const float cim = fmaxf(MARGIN_F + kinv(g_colkey[i]) - d, 0.0f) * (1.0f / (float)(g_colcnt[i] + 1u));
        acc += (double)cs + (double)cim;
    }
    red[threadIdx.x] = acc;
    __syncthreads();
    for (int s2 = 128; s2 > 0; s2 >>= 1){
        if (threadIdx.x < s2) red[threadIdx.x] += red[threadIdx.x + s2];
        __syncthreads();
    }
    if (threadIdx.x == 0) out[0] = (float)red[0];
}

extern "C" void kernel_launch(void* const* d_in, const int* in_sizes, int n_in,
                              void* d_out, int out_size, void* d_ws, size_t ws_size,
                              hipStream_t stream){
    const float* im = (const float*)d_in[0];
    const float* s  = (const float*)d_in[1];
    float* out = (float*)d_out;

    prep_kernel<<<NROWS / 4, 256, 0, stream>>>(im, s);
    gemm_stats_kernel<<<1024, 512, 0, stream>>>();
    finalize_kernel<<<1, 256, 0, stream>>>(out);
}